// Round 1
// baseline (118.316 us; speedup 1.0000x reference)
//
#include <hip/hip_runtime.h>

#define NVAR   576
#define NROW   144
#define DEG    15
#define NBATCH 256
#define NITER  3
#define NT     192            // 3 waves; t<144 owns a row in the decode phase
#define NF4    (NVAR / 4)     // 144 float4 per H row
#define GSTEPS ((NROW * NF4) / (NT * 3))  // 36 scan steps, 3 float4/thread each

// Single fused kernel: one block per batch element.
//  Phase A: per-block H scan (L2/L3-resident, 331 KB) -> column lists via
//           order-free atomic compaction. Order freedom: E_abs only
//           distinguishes the argmin edge; on ties min1==min2, so unordered
//           cols are numerically identical to sorted extraction (we track the
//           min COLUMN ID, not its position).
//  Phase B: row-centric min-sum decode, identical structure to the previous
//           verified kernel (register-resident row state, LDS ping-pong
//           column accumulators, atomic scatter).
// r loads are issued before the scan so their HBM latency hides under it.
__launch_bounds__(NT, 1)
__global__ void ldpc_fused_kernel(const float* __restrict__ r,
                                  const float4* __restrict__ H4,
                                  const float* __restrict__ alpha,
                                  const float* __restrict__ beta,
                                  float* __restrict__ out) {
    __shared__ float rs[NVAR];
    __shared__ float sA[NVAR];        // ping-pong column accumulators
    __shared__ float sB[NVAR];
    __shared__ short colsh[NROW * 16]; // row stride padded to 16 shorts
    __shared__ int   cnt[NROW];

    const int b = blockIdx.x;
    const int t = threadIdx.x;

    float alr[NITER], ber[NITER];
    #pragma unroll
    for (int i = 0; i < NITER; ++i) { alr[i] = alpha[i]; ber[i] = beta[i]; }

    // Zero compaction counters + first accumulator. LDS-only work before the
    // barrier so the barrier's vmcnt drain has nothing global to wait on.
    if (t < NROW) cnt[t] = 0;
    #pragma unroll
    for (int k = 0; k < 3; ++k) sA[t + k * NT] = 0.0f;
    __syncthreads();

    // Issue r loads now; latency hides under the H scan below.
    float rv[3];
    #pragma unroll
    for (int k = 0; k < 3; ++k) rv[k] = r[b * NVAR + t + k * NT];

    // H scan: flat float4 index f = g*576 + j*192 + t; row = f/144 decomposes
    // as 4g + (j*192+t)/144, so the divides are hoisted out of the loop.
    int rj[3], cj[3];
    #pragma unroll
    for (int j = 0; j < 3; ++j) {
        int x = t + j * NT;
        rj[j] = x / NF4;
        cj[j] = (x - rj[j] * NF4) * 4;
    }
    for (int g = 0; g < GSTEPS; ++g) {
        #pragma unroll
        for (int j = 0; j < 3; ++j) {
            float4 v = H4[g * (NT * 3) + j * NT + t];
            int row = (g << 2) + rj[j];
            int cb  = cj[j];
            if (v.x != 0.0f) colsh[row * 16 + atomicAdd(&cnt[row], 1)] = (short)cb;
            if (v.y != 0.0f) colsh[row * 16 + atomicAdd(&cnt[row], 1)] = (short)(cb + 1);
            if (v.z != 0.0f) colsh[row * 16 + atomicAdd(&cnt[row], 1)] = (short)(cb + 2);
            if (v.w != 0.0f) colsh[row * 16 + atomicAdd(&cnt[row], 1)] = (short)(cb + 3);
        }
    }
    #pragma unroll
    for (int k = 0; k < 3; ++k) rs[t + k * NT] = rv[k];
    __syncthreads();   // colsh + rs ready

    // Row-owned register state.
    int   ci[DEG];
    float Mv[DEG], Ev[DEG], rc[DEG];
    if (t < NROW) {
        #pragma unroll
        for (int j = 0; j < DEG; ++j) ci[j] = (int)colsh[t * 16 + j];
        #pragma unroll
        for (int j = 0; j < DEG; ++j) { rc[j] = rs[ci[j]]; Mv[j] = rc[j]; }
    }

    #pragma unroll
    for (int it = 0; it < NITER; ++it) {
        float* sum = (it & 1) ? sB : sA;   // scatter target (pre-zeroed)
        float* nxt = (it & 1) ? sA : sB;   // zeroed this iter for next scatter

        if (t < NROW) {
            // Two-chain min1/min2 reduce (halved dependence depth) + merge.
            // Track the min COLUMN (c1), not the position, so unordered
            // compaction is exactly equivalent.
            float m1a = INFINITY, m2a = INFINITY, m1b = INFINITY, m2b = INFINITY;
            int   c1a = -1,       c1b = -1;
            float sg = 1.0f;
            #pragma unroll
            for (int j = 0; j < 8; ++j) {
                float v = Mv[j];
                float a = fabsf(v);
                sg *= (v > 0.0f) ? 1.0f : ((v < 0.0f) ? -1.0f : 0.0f);
                if (a < m1a) { m2a = m1a; m1a = a; c1a = ci[j]; }
                else if (a < m2a) m2a = a;
            }
            #pragma unroll
            for (int j = 8; j < DEG; ++j) {
                float v = Mv[j];
                float a = fabsf(v);
                sg *= (v > 0.0f) ? 1.0f : ((v < 0.0f) ? -1.0f : 0.0f);
                if (a < m1b) { m2b = m1b; m1b = a; c1b = ci[j]; }
                else if (a < m2b) m2b = a;
            }
            float m1, m2; int c1;
            if (m1b < m1a) { m1 = m1b; c1 = c1b; m2 = fminf(m1a, m2b); }
            else           { m1 = m1a; c1 = c1a; m2 = fminf(m1b, m2a); }

            float asg = alr[it] * sg;
            float th  = ber[it];
            #pragma unroll
            for (int j = 0; j < DEG; ++j) {
                float v = Mv[j];
                float s = (v > 0.0f) ? 1.0f : ((v < 0.0f) ? -1.0f : 0.0f);
                float eabs = (ci[j] == c1) ? m2 : m1;
                float e = asg * s * fmaxf(0.0f, eabs - th);
                Ev[j] = e;
                atomicAdd(&sum[ci[j]], e);
            }
        }
        __syncthreads();   // drain scatter

        if (it == NITER - 1) {
            #pragma unroll
            for (int k = 0; k < 3; ++k) {
                int n = t + k * NT;
                out[b * NVAR + n] = rs[n] + sum[n];
            }
        } else {
            // Zero the other buffer for the next iteration (disjoint from sum).
            #pragma unroll
            for (int k = 0; k < 3; ++k) nxt[t + k * NT] = 0.0f;
            // In-register M update: M = r + sumE - E at this row's columns.
            if (t < NROW) {
                #pragma unroll
                for (int j = 0; j < DEG; ++j)
                    Mv[j] = rc[j] + sum[ci[j]] - Ev[j];
            }
            __syncthreads();
        }
    }
}

extern "C" void kernel_launch(void* const* d_in, const int* in_sizes, int n_in,
                              void* d_out, int out_size, void* d_ws, size_t ws_size,
                              hipStream_t stream) {
    const float* r      = (const float*)d_in[0];
    const float4* H4    = (const float4*)d_in[1];
    const float* alpha  = (const float*)d_in[2];
    const float* beta   = (const float*)d_in[3];
    float* out = (float*)d_out;

    // Single fused dispatch: no build_bits kernel, no workspace round-trip.
    ldpc_fused_kernel<<<NBATCH, NT, 0, stream>>>(r, H4, alpha, beta, out);
}

// Round 2
// 114.675 us; speedup vs baseline: 1.0317x; 1.0317x over previous
//
#include <hip/hip_runtime.h>

#define NVAR   576
#define NROW   144
#define DEG    15
#define NBATCH 256
#define NITER  3
#define NT     576                 // 9 waves: 4 threads per row in decode
#define NWORD  9                   // 576 bits = 9 x 64-bit words per row
#define NWTOT  (NROW * NWORD)      // 1296 bitmask words
#define NWAVE  (NT / 64)           // 9
#define WPW    (NWTOT / NWAVE)     // 144 ballot steps per wave

// Single dispatch, one block per batch element, 9 waves.
//  Phase A (ballot-bits): each wave turns 144 64-float segments of H into
//    64-bit masks: coalesced 256B load + __ballot + one 8B LDS store.
//    No atomics, no divergent component-ifs (the Round-1 mistake), and the
//    144 steps are fully independent so loads pipeline.
//  Phase B (extract): t<144 ffs-extracts its row's 15 cols from LDS bits.
//  Phase C (decode): 4 threads per row. Each owns <=4 edges in registers;
//    min1/min2/argcol/sign merged across the 4-lane group via __shfl_xor.
//    Tie-break is exact: we track the min COLUMN ID, and on ties min1==min2
//    so E_abs is identical regardless of which edge wins the merge.
__launch_bounds__(NT, 1)
__global__ void ldpc_kernel(const float* __restrict__ r,
                            const float* __restrict__ H,
                            const float* __restrict__ alpha,
                            const float* __restrict__ beta,
                            float* __restrict__ out) {
    __shared__ float rs[NVAR];
    __shared__ float sA[NVAR];          // ping-pong column accumulators
    __shared__ float sB[NVAR];
    __shared__ unsigned long long bitsh[NWTOT];   // 10.1 KB row bitmasks
    __shared__ short colsh[NROW * 16];  // row stride padded to 16 shorts

    const int b    = blockIdx.x;
    const int t    = threadIdx.x;
    const int wave = t >> 6;
    const int lane = t & 63;

    float alr[NITER], ber[NITER];
    #pragma unroll
    for (int i = 0; i < NITER; ++i) { alr[i] = alpha[i]; ber[i] = beta[i]; }

    // Stage r (1 float/thread, coalesced; latency hides under ballot loop)
    // and zero the first accumulator.
    rs[t] = r[b * NVAR + t];
    sA[t] = 0.0f;

    // Phase A: ballot-bits. Wave w owns words [w*144, (w+1)*144).
    {
        const float* Hw = H + (wave * WPW) * 64 + lane;
        #pragma unroll 4
        for (int s = 0; s < WPW; ++s) {
            float h = Hw[s * 64];
            unsigned long long m = __ballot(h != 0.0f);
            if (lane == 0) bitsh[wave * WPW + s] = m;
        }
    }
    __syncthreads();   // bitsh + rs ready

    // Phase B: per-row column extraction (ascending; order is irrelevant
    // since the argmin is tracked by column id).
    if (t < NROW) {
        int k = 0;
        #pragma unroll
        for (int i = 0; i < NWORD; ++i) {
            unsigned long long bw = bitsh[t * NWORD + i];
            while (bw) {
                int p = __ffsll((long long)bw) - 1;
                bw &= bw - 1;
                colsh[t * 16 + k] = (short)(i * 64 + p);
                ++k;
            }
        }
    }
    __syncthreads();

    // Phase C: decode. Thread = (row rr, slot e); slot e owns edges
    // j = 4e .. 4e+ne-1 with ne = {4,4,4,3}.
    const int rr = t >> 2;
    const int e  = t & 3;
    const int ne = (e == 3) ? 3 : 4;

    int   ci[4];
    float Mv[4], Ev[4], rc[4];
    #pragma unroll
    for (int jj = 0; jj < 4; ++jj)
        ci[jj] = (jj < ne) ? (int)colsh[rr * 16 + (e * 4 + jj)] : 0;
    #pragma unroll
    for (int jj = 0; jj < 4; ++jj) {
        rc[jj] = rs[ci[jj]];
        Mv[jj] = (jj < ne) ? rc[jj] : INFINITY;   // pad: +inf, sign +1
    }

    #pragma unroll
    for (int it = 0; it < NITER; ++it) {
        float* sum = (it & 1) ? sB : sA;   // scatter target (pre-zeroed)
        float* nxt = (it & 1) ? sA : sB;   // zeroed this iter for next scatter

        // Per-thread partial min1/min2/argcol/sign over <=4 edges.
        float m1 = INFINITY, m2 = INFINITY, sg = 1.0f;
        int   c1 = -1;
        #pragma unroll
        for (int jj = 0; jj < 4; ++jj) {
            float v = Mv[jj];
            float a = fabsf(v);
            sg *= (v > 0.0f) ? 1.0f : ((v < 0.0f) ? -1.0f : 0.0f);
            if (a < m1) { m2 = m1; m1 = a; c1 = ci[jj]; }
            else if (a < m2) m2 = a;
        }
        // Merge across the 4-lane row group (lanes rr*4 .. rr*4+3).
        #pragma unroll
        for (int d = 1; d <= 2; d <<= 1) {
            float om1 = __shfl_xor(m1, d);
            float om2 = __shfl_xor(m2, d);
            int   oc1 = __shfl_xor(c1, d);
            float osg = __shfl_xor(sg, d);
            sg *= osg;
            if (om1 < m1) { m2 = fminf(m1, om2); m1 = om1; c1 = oc1; }
            else          { m2 = fminf(m2, om1); }
        }

        // E values + column scatter (E stays in registers).
        float asg = alr[it] * sg;
        float th  = ber[it];
        #pragma unroll
        for (int jj = 0; jj < 4; ++jj) {
            float v = Mv[jj];
            float s = (v > 0.0f) ? 1.0f : ((v < 0.0f) ? -1.0f : 0.0f);
            float eabs = (ci[jj] == c1) ? m2 : m1;
            float ev = asg * s * fmaxf(0.0f, eabs - th);
            Ev[jj] = ev;
            if (jj < ne) atomicAdd(&sum[ci[jj]], ev);
        }
        __syncthreads();   // drain scatter

        if (it == NITER - 1) {
            out[b * NVAR + t] = rs[t] + sum[t];
        } else {
            nxt[t] = 0.0f;   // zero the other buffer (disjoint from sum)
            // In-register M update: M = r + sumE - E at this thread's edges.
            #pragma unroll
            for (int jj = 0; jj < 4; ++jj)
                if (jj < ne) Mv[jj] = rc[jj] + sum[ci[jj]] - Ev[jj];
            __syncthreads();
        }
    }
}

extern "C" void kernel_launch(void* const* d_in, const int* in_sizes, int n_in,
                              void* d_out, int out_size, void* d_ws, size_t ws_size,
                              hipStream_t stream) {
    const float* r     = (const float*)d_in[0];
    const float* H     = (const float*)d_in[1];
    const float* alpha = (const float*)d_in[2];
    const float* beta  = (const float*)d_in[3];
    float* out = (float*)d_out;

    ldpc_kernel<<<NBATCH, NT, 0, stream>>>(r, H, alpha, beta, out);
}

// Round 3
// 78.740 us; speedup vs baseline: 1.5026x; 1.4564x over previous
//
#include <hip/hip_runtime.h>

#define NVAR   576
#define NROW   144
#define DEG    15
#define NBATCH 256
#define NITER  3
#define NT     576                 // 9 waves: 4 threads per row in decode
#define NWORD  9                   // 576 bits = 9 x 64-bit words per row
#define NWTOT  (NROW * NWORD)      // 1296 bitmask words
#define NWAVE  (NT / 64)           // 9
#define WPW    (NWTOT / NWAVE)     // 144 ballot words per wave
#define BATCH  16                  // independent loads in flight per batch
#define NBAT   (WPW / BATCH)       // 9 batches -> 9 latency exposures total

// Single dispatch, one block per batch element, 9 waves.
//  Phase A (ballot-bits, MLP-batched): each wave turns its 144 64-float
//    segments of H into 64-bit masks. 16 loads are issued back-to-back into
//    registers (independent, base+imm-offset), THEN 16 ballots consume them:
//    chain depth = 9 load latencies total, vs 36+ in Round 2. Batch order is
//    rotated by blockIdx so 256 blocks don't hit the same L2 sets in lockstep.
//  Phase B (extract): t<144 ffs-extracts its row's 15 cols from LDS bits.
//  Phase C (decode): 4 threads per row, register-resident edges,
//    min1/min2/argcol/sign merged via 4-lane __shfl_xor. Tie-break exact:
//    min tracked by COLUMN ID; on ties min1==min2 so E_abs is identical.
__launch_bounds__(NT, 1)
__global__ void ldpc_kernel(const float* __restrict__ r,
                            const float* __restrict__ H,
                            const float* __restrict__ alpha,
                            const float* __restrict__ beta,
                            float* __restrict__ out) {
    __shared__ float rs[NVAR];
    __shared__ float sA[NVAR];          // ping-pong column accumulators
    __shared__ float sB[NVAR];
    __shared__ unsigned long long bitsh[NWTOT];   // 10.1 KB row bitmasks
    __shared__ short colsh[NROW * 16];  // row stride padded to 16 shorts

    const int b    = blockIdx.x;
    const int t    = threadIdx.x;
    const int wave = t >> 6;
    const int lane = t & 63;

    // Issue r + alpha/beta loads now; consumed only after Phase A, so their
    // latency hides under the scan. (R2 wrote rs[t] here -> vmcnt stall
    // BEFORE the scan. Keep the value in a register instead.)
    float rv = r[b * NVAR + t];
    float alr[NITER], ber[NITER];
    #pragma unroll
    for (int i = 0; i < NITER; ++i) { alr[i] = alpha[i]; ber[i] = beta[i]; }

    sA[t] = 0.0f;   // zero first accumulator (LDS-only, no barrier needed yet)

    // Phase A: batched ballot-bits. Wave w owns words [w*144, (w+1)*144).
    {
        const float* Hw = H + (wave * WPW) * 64 + lane;
        #pragma unroll
        for (int bb = 0; bb < NBAT; ++bb) {
            const int base = ((bb + b) % NBAT) * BATCH;   // block-rotated order
            float hv[BATCH];
            #pragma unroll
            for (int u = 0; u < BATCH; ++u)
                hv[u] = Hw[(base + u) * 64];              // 16 independent loads
            #pragma unroll
            for (int u = 0; u < BATCH; ++u) {
                unsigned long long m = __ballot(hv[u] != 0.0f);
                if (lane == 0) bitsh[wave * WPW + base + u] = m;
            }
        }
    }
    rs[t] = rv;
    __syncthreads();   // bitsh + rs ready

    // Phase B: per-row column extraction (order irrelevant: argmin tracked
    // by column id, and on ties min1==min2).
    if (t < NROW) {
        int k = 0;
        #pragma unroll
        for (int i = 0; i < NWORD; ++i) {
            unsigned long long bw = bitsh[t * NWORD + i];
            while (bw) {
                int p = __ffsll((long long)bw) - 1;
                bw &= bw - 1;
                colsh[t * 16 + k] = (short)(i * 64 + p);
                ++k;
            }
        }
    }
    __syncthreads();

    // Phase C: decode. Thread = (row rr, slot e); slot e owns edges
    // j = 4e .. 4e+ne-1 with ne = {4,4,4,3}.
    const int rr = t >> 2;
    const int e  = t & 3;
    const int ne = (e == 3) ? 3 : 4;

    int   ci[4];
    float Mv[4], Ev[4], rc[4];
    #pragma unroll
    for (int jj = 0; jj < 4; ++jj)
        ci[jj] = (jj < ne) ? (int)colsh[rr * 16 + (e * 4 + jj)] : 0;
    #pragma unroll
    for (int jj = 0; jj < 4; ++jj) {
        rc[jj] = rs[ci[jj]];
        Mv[jj] = (jj < ne) ? rc[jj] : INFINITY;   // pad: +inf, sign +1
    }

    #pragma unroll
    for (int it = 0; it < NITER; ++it) {
        float* sum = (it & 1) ? sB : sA;   // scatter target (pre-zeroed)
        float* nxt = (it & 1) ? sA : sB;   // zeroed this iter for next scatter

        // Per-thread partial min1/min2/argcol/sign over <=4 edges.
        float m1 = INFINITY, m2 = INFINITY, sg = 1.0f;
        int   c1 = -1;
        #pragma unroll
        for (int jj = 0; jj < 4; ++jj) {
            float v = Mv[jj];
            float a = fabsf(v);
            sg *= (v > 0.0f) ? 1.0f : ((v < 0.0f) ? -1.0f : 0.0f);
            if (a < m1) { m2 = m1; m1 = a; c1 = ci[jj]; }
            else if (a < m2) m2 = a;
        }
        // Merge across the 4-lane row group (lanes rr*4 .. rr*4+3).
        #pragma unroll
        for (int d = 1; d <= 2; d <<= 1) {
            float om1 = __shfl_xor(m1, d);
            float om2 = __shfl_xor(m2, d);
            int   oc1 = __shfl_xor(c1, d);
            float osg = __shfl_xor(sg, d);
            sg *= osg;
            if (om1 < m1) { m2 = fminf(m1, om2); m1 = om1; c1 = oc1; }
            else          { m2 = fminf(m2, om1); }
        }

        // E values + column scatter (E stays in registers).
        float asg = alr[it] * sg;
        float th  = ber[it];
        #pragma unroll
        for (int jj = 0; jj < 4; ++jj) {
            float v = Mv[jj];
            float s = (v > 0.0f) ? 1.0f : ((v < 0.0f) ? -1.0f : 0.0f);
            float eabs = (ci[jj] == c1) ? m2 : m1;
            float ev = asg * s * fmaxf(0.0f, eabs - th);
            Ev[jj] = ev;
            if (jj < ne) atomicAdd(&sum[ci[jj]], ev);
        }
        __syncthreads();   // drain scatter

        if (it == NITER - 1) {
            out[b * NVAR + t] = rs[t] + sum[t];
        } else {
            nxt[t] = 0.0f;   // zero the other buffer (disjoint from sum)
            // In-register M update: M = r + sumE - E at this thread's edges.
            #pragma unroll
            for (int jj = 0; jj < 4; ++jj)
                if (jj < ne) Mv[jj] = rc[jj] + sum[ci[jj]] - Ev[jj];
            __syncthreads();
        }
    }
}

extern "C" void kernel_launch(void* const* d_in, const int* in_sizes, int n_in,
                              void* d_out, int out_size, void* d_ws, size_t ws_size,
                              hipStream_t stream) {
    const float* r     = (const float*)d_in[0];
    const float* H     = (const float*)d_in[1];
    const float* alpha = (const float*)d_in[2];
    const float* beta  = (const float*)d_in[3];
    float* out = (float*)d_out;

    ldpc_kernel<<<NBATCH, NT, 0, stream>>>(r, H, alpha, beta, out);
}

// Round 4
// 78.425 us; speedup vs baseline: 1.5087x; 1.0040x over previous
//
#include <hip/hip_runtime.h>

#define NVAR   576
#define NROW   144
#define DEG    15
#define NBATCH 256
#define NITER  3
#define NT     576                 // 9 waves: 4 threads per row in decode
#define NWORD  9                   // 576 bits = 9 x 64-bit words per row
#define NWTOT  (NROW * NWORD)      // 1296 bitmask words
#define NWAVE  (NT / 64)           // 9
#define WPW    (NWTOT / NWAVE)     // 144 ballot words per wave
#define BATCH  48                  // independent loads in flight per batch
#define NBAT   (WPW / BATCH)       // 3 batches -> 3 cold-latency exposures

// Single dispatch, one block per batch element, 9 waves.
// The harness's per-iteration 256 MiB poison fill overwrites L2+L3 exactly,
// so H and r are COLD every run: the kernel is bound by cold-miss latency
// exposures, not bandwidth (aggregate HBM fetch is ~3 MB). Hence:
//  - Phase A issues 48 independent loads per batch (3 exposures total, was 9),
//  - all blocks scan H in IDENTICAL order (no blockIdx rotation) so the 8
//    XCD L2s' MSHRs coalesce the shared 331 KB read across blocks on cold
//    start (the R3 rotation scattered requests and defeated this).
//  Phase B (extract): t<144 ffs-extracts its row's 15 cols from LDS bits.
//  Phase C (decode): 4 threads per row, register-resident edges,
//    min1/min2/argcol/sign merged via 4-lane __shfl_xor. Tie-break exact:
//    min tracked by COLUMN ID; on ties min1==min2 so E_abs is identical.
__launch_bounds__(NT, 1)
__global__ void ldpc_kernel(const float* __restrict__ r,
                            const float* __restrict__ H,
                            const float* __restrict__ alpha,
                            const float* __restrict__ beta,
                            float* __restrict__ out) {
    __shared__ float rs[NVAR];
    __shared__ float sA[NVAR];          // ping-pong column accumulators
    __shared__ float sB[NVAR];
    __shared__ unsigned long long bitsh[NWTOT];   // 10.1 KB row bitmasks
    __shared__ short colsh[NROW * 16];  // row stride padded to 16 shorts

    const int b    = blockIdx.x;
    const int t    = threadIdx.x;
    const int wave = t >> 6;
    const int lane = t & 63;

    const float* Hw = H + (wave * WPW) * 64 + lane;

    // Issue the first H batch as early as possible, then r/alpha/beta —
    // everything cold-misses, so get all first-exposure requests in flight
    // before anything consumes them.
    float hv0[BATCH];
    #pragma unroll
    for (int u = 0; u < BATCH; ++u) hv0[u] = Hw[u * 64];

    float rv = r[b * NVAR + t];
    float alr[NITER], ber[NITER];
    #pragma unroll
    for (int i = 0; i < NITER; ++i) { alr[i] = alpha[i]; ber[i] = beta[i]; }

    sA[t] = 0.0f;   // zero first accumulator (LDS-only, doesn't wait on vmem)

    // Phase A: batched ballot-bits. Wave w owns words [w*144, (w+1)*144).
    #pragma unroll
    for (int bb = 0; bb < NBAT; ++bb) {
        const int base = bb * BATCH;    // identical order across all blocks
        float hv[BATCH];
        if (bb == 0) {
            #pragma unroll
            for (int u = 0; u < BATCH; ++u) hv[u] = hv0[u];
        } else {
            const float* Hs = Hw + base * 64;
            #pragma unroll
            for (int u = 0; u < BATCH; ++u) hv[u] = Hs[u * 64];
        }
        #pragma unroll
        for (int u = 0; u < BATCH; ++u) {
            unsigned long long m = __ballot(hv[u] != 0.0f);
            if (lane == 0) bitsh[wave * WPW + base + u] = m;
        }
    }
    rs[t] = rv;
    __syncthreads();   // bitsh + rs ready

    // Phase B: per-row column extraction (order irrelevant: argmin tracked
    // by column id, and on ties min1==min2).
    if (t < NROW) {
        int k = 0;
        #pragma unroll
        for (int i = 0; i < NWORD; ++i) {
            unsigned long long bw = bitsh[t * NWORD + i];
            while (bw) {
                int p = __ffsll((long long)bw) - 1;
                bw &= bw - 1;
                colsh[t * 16 + k] = (short)(i * 64 + p);
                ++k;
            }
        }
    }
    __syncthreads();

    // Phase C: decode. Thread = (row rr, slot e); slot e owns edges
    // j = 4e .. 4e+ne-1 with ne = {4,4,4,3}.
    const int rr = t >> 2;
    const int e  = t & 3;
    const int ne = (e == 3) ? 3 : 4;

    int   ci[4];
    float Mv[4], Ev[4], rc[4];
    #pragma unroll
    for (int jj = 0; jj < 4; ++jj)
        ci[jj] = (jj < ne) ? (int)colsh[rr * 16 + (e * 4 + jj)] : 0;
    #pragma unroll
    for (int jj = 0; jj < 4; ++jj) {
        rc[jj] = rs[ci[jj]];
        Mv[jj] = (jj < ne) ? rc[jj] : INFINITY;   // pad: +inf, sign +1
    }

    #pragma unroll
    for (int it = 0; it < NITER; ++it) {
        float* sum = (it & 1) ? sB : sA;   // scatter target (pre-zeroed)
        float* nxt = (it & 1) ? sA : sB;   // zeroed this iter for next scatter

        // Per-thread partial min1/min2/argcol/sign over <=4 edges.
        float m1 = INFINITY, m2 = INFINITY, sg = 1.0f;
        int   c1 = -1;
        #pragma unroll
        for (int jj = 0; jj < 4; ++jj) {
            float v = Mv[jj];
            float a = fabsf(v);
            sg *= (v > 0.0f) ? 1.0f : ((v < 0.0f) ? -1.0f : 0.0f);
            if (a < m1) { m2 = m1; m1 = a; c1 = ci[jj]; }
            else if (a < m2) m2 = a;
        }
        // Merge across the 4-lane row group (lanes rr*4 .. rr*4+3).
        #pragma unroll
        for (int d = 1; d <= 2; d <<= 1) {
            float om1 = __shfl_xor(m1, d);
            float om2 = __shfl_xor(m2, d);
            int   oc1 = __shfl_xor(c1, d);
            float osg = __shfl_xor(sg, d);
            sg *= osg;
            if (om1 < m1) { m2 = fminf(m1, om2); m1 = om1; c1 = oc1; }
            else          { m2 = fminf(m2, om1); }
        }

        // E values + column scatter (E stays in registers).
        float asg = alr[it] * sg;
        float th  = ber[it];
        #pragma unroll
        for (int jj = 0; jj < 4; ++jj) {
            float v = Mv[jj];
            float s = (v > 0.0f) ? 1.0f : ((v < 0.0f) ? -1.0f : 0.0f);
            float eabs = (ci[jj] == c1) ? m2 : m1;
            float ev = asg * s * fmaxf(0.0f, eabs - th);
            Ev[jj] = ev;
            if (jj < ne) atomicAdd(&sum[ci[jj]], ev);
        }
        __syncthreads();   // drain scatter

        if (it == NITER - 1) {
            out[b * NVAR + t] = rs[t] + sum[t];
        } else {
            nxt[t] = 0.0f;   // zero the other buffer (disjoint from sum)
            // In-register M update: M = r + sumE - E at this thread's edges.
            #pragma unroll
            for (int jj = 0; jj < 4; ++jj)
                if (jj < ne) Mv[jj] = rc[jj] + sum[ci[jj]] - Ev[jj];
            __syncthreads();
        }
    }
}

extern "C" void kernel_launch(void* const* d_in, const int* in_sizes, int n_in,
                              void* d_out, int out_size, void* d_ws, size_t ws_size,
                              hipStream_t stream) {
    const float* r     = (const float*)d_in[0];
    const float* H     = (const float*)d_in[1];
    const float* alpha = (const float*)d_in[2];
    const float* beta  = (const float*)d_in[3];
    float* out = (float*)d_out;

    ldpc_kernel<<<NBATCH, NT, 0, stream>>>(r, H, alpha, beta, out);
}